// Round 6
// baseline (3229.814 us; speedup 1.0000x reference)
//
#include <hip/hip_runtime.h>
#include <hip/hip_bf16.h>

typedef unsigned short u16;
typedef unsigned long long u64;
typedef short bf16x8 __attribute__((ext_vector_type(8)));
typedef float f32x4 __attribute__((ext_vector_type(4)));

__device__ __forceinline__ float ldbf(const u16* p) {
    __hip_bfloat16 h = *(const __hip_bfloat16*)p;
    return __bfloat162float(h);
}
__device__ __forceinline__ void stbf(u16* p, float f) {
    *(__hip_bfloat16*)p = __float2bfloat16(f);
}
__device__ __forceinline__ unsigned f2bfu(float f) {
    __hip_bfloat16 h = __float2bfloat16(f);
    return (unsigned)*(u16*)&h;
}
__device__ __forceinline__ float bf2f(u16 v) {
    union { unsigned u; float f; } x; x.u = ((unsigned)v) << 16; return x.f;
}
__device__ __forceinline__ float sigm(float x) {
    return 1.0f / (1.0f + __expf(-x));
}
// saturation-correct fast tanh
__device__ __forceinline__ float tanh_fast(float x) {
    float e = __expf(2.0f * x);
    return 1.0f - 2.0f / (e + 1.0f);
}

// ---------------------------------------------------------------------------
// f32 -> bf16 conversion (for w_hh)
// ---------------------------------------------------------------------------
__global__ __launch_bounds__(256) void cvt_bf16(const float* __restrict__ in,
                                                u16* __restrict__ out, int n) {
    int i = blockIdx.x * 256 + threadIdx.x;
    if (i < n) stbf(out + i, in[i]);
}

// ---------------------------------------------------------------------------
// Upsample conv (unchanged)
// ---------------------------------------------------------------------------
template <bool INF32>
__global__ __launch_bounds__(256) void upsample(const void* __restrict__ in_,
                                                const float* __restrict__ w,
                                                const float* __restrict__ bias_,
                                                u16* __restrict__ out,
                                                int Lin, int shift) {
    const int Cin = 1024 >> shift;
    const int total = 2 * Lin * 128 * 512;
    int idx = blockIdx.x * 256 + threadIdx.x;
    if (idx >= total) return;
    const int c  = idx & 511;
    const int bb = (idx >> 9) & 127;
    const int tp = idx >> 16;          // t = 2l + s
    const int s  = tp & 1;
    const int l  = tp >> 1;
    const int oc = c + (s << 9);
    const int ch = oc >> shift;
    float acc = bias_[oc];
    #pragma unroll
    for (int k = 0; k < 7; ++k) {
        int li = l + k - 3;
        if (li >= 0 && li < Lin) {
            size_t off = ((size_t)li * 128 + bb) * Cin + ch;
            float v = INF32 ? ((const float*)in_)[off] : ldbf((const u16*)in_ + off);
            acc += w[oc * 7 + k] * v;
        }
    }
    stbf(out + idx, fmaxf(acc, 0.0f));
}

// ---------------------------------------------------------------------------
// gates_x GEMM (MFMA). Output layout [t][jt(32)][b(128)][g(4)][jr(16)].
// (unchanged)
// ---------------------------------------------------------------------------
__global__ __launch_bounds__(256) void gemm_gates(const float* __restrict__ x,
                                                  const u16* __restrict__ z2,
                                                  const float* __restrict__ wih,
                                                  const float* __restrict__ bih,
                                                  const float* __restrict__ bhh,
                                                  u16* __restrict__ gates) {
    __shared__ __align__(16) u16 smA[128 * 32];
    __shared__ __align__(16) u16 smB[128 * 32];
    const int tid  = threadIdx.x;
    const int lane = tid & 63;
    const int wave = tid >> 6;
    const int wm = wave >> 1, wn = wave & 1;
    const size_t mbase = (size_t)blockIdx.x * 128;
    const size_t nbase = (size_t)blockIdx.y * 128;

    f32x4 acc[4][4] = {};

    const int srow = tid >> 1;            // staging row 0..127
    const int scol = (tid & 1) * 16;      // staging col 0 or 16

    for (int kt = 0; kt < 32; ++kt) {
        const int kb = kt * 32;
        // stage A tile [128][32]
        if (kb < 512) {
            const float* src = x + (mbase + srow) * 512 + kb + scol;
            alignas(16) u16 tmp[16];
            #pragma unroll
            for (int q = 0; q < 16; ++q) stbf(&tmp[q], src[q]);
            *(int4*)&smA[srow * 32 + scol]     = *(const int4*)&tmp[0];
            *(int4*)&smA[srow * 32 + scol + 8] = *(const int4*)&tmp[8];
        } else {
            const u16* src = z2 + 65536 + (mbase + srow) * 512 + (kb - 512) + scol;
            *(int4*)&smA[srow * 32 + scol]     = *(const int4*)(src);
            *(int4*)&smA[srow * 32 + scol + 8] = *(const int4*)(src + 8);
        }
        // stage B tile [128][32] from f32 w_ih [2048][1024]
        {
            const float* src = wih + (nbase + srow) * 1024 + kb + scol;
            alignas(16) u16 tmp[16];
            #pragma unroll
            for (int q = 0; q < 16; ++q) stbf(&tmp[q], src[q]);
            *(int4*)&smB[srow * 32 + scol]     = *(const int4*)&tmp[0];
            *(int4*)&smB[srow * 32 + scol + 8] = *(const int4*)&tmp[8];
        }
        __syncthreads();

        bf16x8 af[4], bfr[4];
        #pragma unroll
        for (int mi = 0; mi < 4; ++mi)
            af[mi] = *(const bf16x8*)&smA[(wm * 64 + mi * 16 + (lane & 15)) * 32 + (lane >> 4) * 8];
        #pragma unroll
        for (int ni = 0; ni < 4; ++ni)
            bfr[ni] = *(const bf16x8*)&smB[(wn * 64 + ni * 16 + (lane & 15)) * 32 + (lane >> 4) * 8];
        #pragma unroll
        for (int mi = 0; mi < 4; ++mi)
            #pragma unroll
            for (int ni = 0; ni < 4; ++ni)
                acc[mi][ni] = __builtin_amdgcn_mfma_f32_16x16x32_bf16(af[mi], bfr[ni], acc[mi][ni], 0, 0, 0);
        __syncthreads();
    }

    // epilogue: C/D layout col = lane&15, row = (lane>>4)*4 + r
    u16* gt = gates + (size_t)blockIdx.x * 262144;
    #pragma unroll
    for (int ni = 0; ni < 4; ++ni) {
        const int n = (int)nbase + wn * 64 + ni * 16 + (lane & 15);
        const float bias = bih[n] + bhh[n];
        const int g  = n >> 9;
        const int jh = n & 511;
        u16* gb = gt + (size_t)(jh >> 4) * 8192 + (size_t)(g * 16 + (jh & 15));
        #pragma unroll
        for (int mi = 0; mi < 4; ++mi) {
            const int b = wm * 64 + mi * 16 + (lane >> 4) * 4;
            #pragma unroll
            for (int r = 0; r < 4; ++r)
                stbf(gb + (size_t)(b + r) * 64, acc[mi][ni][r] + bias);
        }
    }
}

// ---------------------------------------------------------------------------
// Persistent LSTM, round 6: SELF-VALIDATING TAGGED h EXCHANGE (no flags, no
// store-ack, no barrier). h buffer = u32/elem {hi16=step tag, lo16=bf16 h}.
// Producers fire relaxed agent-scope tagged stores and proceed; consumers
// poll the data itself (batched u64 atomic loads, re-poll only pending
// chunks; accept when both embedded tags == t). Ping-pong buffers make the
// overwrite race impossible: tag t+2 can only be written to buffer[t&1]
// after all group peers published t+1, which requires them to have fully
// consumed t (2-deep pipeline invariant).
// Topology: 8 groups x 16 blocks; block = 16 batches x 32 j-cols. w_hh
// fragments entirely in registers (128 VGPR, loaded once). gx prefetched a
// full step ahead. Critical path/step = store flight + 1 poll RT + MFMA + ew.
// ---------------------------------------------------------------------------
__global__ __launch_bounds__(256) void lstm_persist(const u16* __restrict__ gates,
                                                    const u16* __restrict__ whh,
                                                    unsigned* __restrict__ hbuf,
                                                    float* __restrict__ out) {
    __shared__ __align__(16) u16 smH[16 * 512];        // [16 b][512 k] swizzled, 16 KB
    __shared__ __align__(16) float smG[4 * 16 * 33];   // [4 g][16 b][32 j + pad]

    const int tid  = threadIdx.x;
    const int lane = tid & 63;
    const int wave = tid >> 6;                 // gate group i,f,g,o
    const int bid  = blockIdx.x;
    const int grp  = bid >> 4;                 // batch group 0..7
    const int jt   = bid & 15;                 // j-tile 0..15 (32 cols)
    const int b0   = grp << 4;                 // 16 batches
    const int jh0  = jt << 5;                  // 32 j-cols

    const int fr = lane & 15;                  // fragment row-in-tile
    const int kq = lane >> 4;                  // k quad
    const int br = tid >> 4;                   // elementwise batch row 0..15
    const int j2 = (tid & 15) * 2;             // elementwise col pair 0..30

    // ---- w_hh fragments -> registers, once (2 n-subtiles x 16 k-frags) ----
    bf16x8 wf0[16], wf1[16];
    {
        const int n0 = wave * 512 + jh0 + fr;        // subtile 0: +0
        const int n1 = n0 + 16;                      // subtile 1: +16
        #pragma unroll
        for (int kt = 0; kt < 16; ++kt) {
            wf0[kt] = *(const bf16x8*)(whh + (size_t)n0 * 512 + kt * 32 + kq * 8);
            wf1[kt] = *(const bf16x8*)(whh + (size_t)n1 * 512 + kt * 32 + kq * 8);
        }
    }

    // per-thread gx base offset (gates layout [t][jt16][b][g][jr])
    const size_t gxoff = (size_t)(jt * 2 + (j2 >> 4)) * 8192
                       + (size_t)(b0 + br) * 64 + (j2 & 15);
    unsigned gxn[4];
    #pragma unroll
    for (int g = 0; g < 4; ++g)
        gxn[g] = *(const unsigned*)(gates + gxoff + g * 16);

    float cA = 0.0f, cB = 0.0f;                // c-state (cols j2, j2+1)
    const int axor = (fr & 7) << 4;

    for (int t = 0; t < 511; ++t) {
        // ---- rotate gx and prefetch next step's (hides full HBM latency) ----
        unsigned gxc[4];
        #pragma unroll
        for (int g = 0; g < 4; ++g) gxc[g] = gxn[g];
        {
            const int tn = (t < 510) ? t + 1 : t;
            const u16* gsrc = gates + (size_t)tn * 262144 + gxoff;
            #pragma unroll
            for (int g = 0; g < 4; ++g)
                gxn[g] = *(const unsigned*)(gsrc + g * 16);
        }

        // ---- poll tagged h tile [16][512]: 16 u64 chunks per thread ----
        {
            const u64* hp = (const u64*)(hbuf + (size_t)(t & 1) * 65536
                                              + (size_t)b0 * 512);
            const unsigned tg = (unsigned)t;
            unsigned pend = 0xffffu;
            do {
                u64 v[16];
                #pragma unroll
                for (int i = 0; i < 16; ++i)
                    if (pend & (1u << i))
                        v[i] = __hip_atomic_load(hp + i * 256 + tid,
                                                 __ATOMIC_RELAXED,
                                                 __HIP_MEMORY_SCOPE_AGENT);
                #pragma unroll
                for (int i = 0; i < 16; ++i)
                    if (pend & (1u << i)) {
                        const unsigned lo = (unsigned)v[i];
                        const unsigned hi = (unsigned)(v[i] >> 32);
                        if (((lo >> 16) == tg) & ((hi >> 16) == tg)) {
                            const int e2  = (i * 256 + tid) * 2;
                            const int row = e2 >> 9;
                            const int c   = e2 & 511;
                            *(unsigned*)((char*)smH +
                                ((row * 1024 + c * 2) ^ ((row & 7) << 4))) =
                                (lo & 0xffffu) | (hi << 16);
                            pend &= ~(1u << i);
                        }
                    }
            } while (pend);
        }
        __syncthreads();

        // ---- gates GEMM: wave g computes [16 b][32 j] of gate g, K=512 ----
        f32x4 acc0 = {}, acc1 = {};
        #pragma unroll
        for (int kt = 0; kt < 16; ++kt) {
            bf16x8 a = *(const bf16x8*)((const char*)smH +
                        ((fr * 1024 + kt * 64 + kq * 16) ^ axor));
            acc0 = __builtin_amdgcn_mfma_f32_16x16x32_bf16(a, wf0[kt], acc0, 0, 0, 0);
            acc1 = __builtin_amdgcn_mfma_f32_16x16x32_bf16(a, wf1[kt], acc1, 0, 0, 0);
        }

        // ---- dump gates to LDS: batch = kq*4+r, j = ni*16 + fr ----
        #pragma unroll
        for (int r = 0; r < 4; ++r) {
            smG[(wave * 16 + kq * 4 + r) * 33 + fr]      = acc0[r];
            smG[(wave * 16 + kq * 4 + r) * 33 + 16 + fr] = acc1[r];
        }
        __syncthreads();

        // ---- elementwise LSTM: thread owns (br, j2) and (br, j2+1) ----
        float hn0, hn1;
        {
            const float gi = smG[(0 * 16 + br) * 33 + j2] + bf2f((u16)(gxc[0] & 0xffff));
            const float gf = smG[(1 * 16 + br) * 33 + j2] + bf2f((u16)(gxc[1] & 0xffff));
            const float gg = smG[(2 * 16 + br) * 33 + j2] + bf2f((u16)(gxc[2] & 0xffff));
            const float go = smG[(3 * 16 + br) * 33 + j2] + bf2f((u16)(gxc[3] & 0xffff));
            cA = sigm(gf) * cA + sigm(gi) * tanh_fast(gg);
            hn0 = sigm(go) * tanh_fast(cA);
        }
        {
            const float gi = smG[(0 * 16 + br) * 33 + j2 + 1] + bf2f((u16)(gxc[0] >> 16));
            const float gf = smG[(1 * 16 + br) * 33 + j2 + 1] + bf2f((u16)(gxc[1] >> 16));
            const float gg = smG[(2 * 16 + br) * 33 + j2 + 1] + bf2f((u16)(gxc[2] >> 16));
            const float go = smG[(3 * 16 + br) * 33 + j2 + 1] + bf2f((u16)(gxc[3] >> 16));
            cB = sigm(gf) * cB + sigm(gi) * tanh_fast(gg);
            hn1 = sigm(go) * tanh_fast(cB);
        }
        // ---- tagged h store (fire and forget) + plain out store ----
        {
            const unsigned tg1 = (unsigned)(t + 1) << 16;
            const unsigned w0 = f2bfu(hn0) | tg1;
            const unsigned w1 = f2bfu(hn1) | tg1;
            unsigned* hb = hbuf + (size_t)((t + 1) & 1) * 65536
                                + (size_t)(b0 + br) * 512 + jh0 + j2;
            __hip_atomic_store((u64*)hb, (u64)w0 | ((u64)w1 << 32),
                               __ATOMIC_RELAXED, __HIP_MEMORY_SCOPE_AGENT);
        }
        float* odst = out + ((size_t)t * 128 + b0 + br) * 512 + jh0;
        *(float2*)(odst + j2) = make_float2(hn0, hn1);
    }
}

// ---------------------------------------------------------------------------
extern "C" void kernel_launch(void* const* d_in, const int* in_sizes, int n_in,
                              void* d_out, int out_size, void* d_ws, size_t ws_size,
                              hipStream_t stream) {
    const float* x   = (const float*)d_in[0];
    const float* z   = (const float*)d_in[1];
    const float* c0w = (const float*)d_in[2];
    const float* c0b = (const float*)d_in[3];
    const float* c1w = (const float*)d_in[4];
    const float* c1b = (const float*)d_in[5];
    const float* wih = (const float*)d_in[6];
    const float* whh = (const float*)d_in[7];
    const float* bih = (const float*)d_in[8];
    const float* bhh = (const float*)d_in[9];
    float* out = (float*)d_out;                // f32 output (reference dtype)
    char* ws = (char*)d_ws;

    // workspace layout (bytes) — total 371,195,904 (unchanged)
    u16*      z1     = (u16*)(ws);              //  33,554,432 B: [256][128][512] bf16
    u16*      z2     = (u16*)(ws + 33554432);   //  67,108,864 B: [512][128][512] bf16
    u16*      gates  = (u16*)(ws + 100663296);  // 267,911,168 B: [511][32][128][4][16] bf16
    unsigned* hbuf   = (unsigned*)(ws + 368574464); // 524,288 B: [2][128][512] tagged u32
    u16*      whh_bf = (u16*)(ws + 369098752);  //   2,097,152 B: [2048][512] bf16

    hipMemsetAsync(hbuf, 0, 262144, stream);    // buffer[0]: h=0, tag=0

    // convert w_hh to bf16
    cvt_bf16<<<dim3(4096), 256, 0, stream>>>(whh, whh_bf, 1048576);

    // upsample x2
    upsample<true ><<<dim3(16777216 / 256), 256, 0, stream>>>(z,  c0w, c0b, z1, 128, 2);
    upsample<false><<<dim3(33554432 / 256), 256, 0, stream>>>(z1, c1w, c1b, z2, 256, 1);

    // gates_x = [x[:-1] | z2[1:]] @ w_ih^T + b_ih + b_hh  (tiled layout)
    gemm_gates<<<dim3(511, 16), 256, 0, stream>>>(x, z2, wih, bih, bhh, gates);

    // whole recurrence in one cooperative persistent kernel
    {
        const u16* gates_a = gates;
        const u16* whh_a   = whh_bf;
        unsigned*  hbuf_a  = hbuf;
        float*     out_a   = out;
        void* args[] = {&gates_a, &whh_a, &hbuf_a, &out_a};
        hipLaunchCooperativeKernel((void*)lstm_persist, dim3(128), dim3(256),
                                   args, 0, stream);
    }
}